// Round 4
// baseline (286.358 us; speedup 1.0000x reference)
//
#include <hip/hip_runtime.h>
#include <stdint.h>

// Shapes (fixed by the problem)
#define Bn 256
#define Un 128
#define Pn 64
#define Hn 768
#define Ototal 192   // 128 row-logit outputs + 64 col-logit outputs
#define KC 16        // split-K chunks in phase B (K=8192 -> 512 each)

#define LDC 264      // phaseA LDS row stride (ushorts): 528B = 33*16 (b128-aligned)
#define LDB 72       // phaseB LDS row stride (ushorts): 144B = 9*16 (b128-aligned)

typedef short s4v __attribute__((ext_vector_type(4)));
typedef short s8v __attribute__((ext_vector_type(8)));
typedef float f4v __attribute__((ext_vector_type(4)));

__device__ __forceinline__ short f2bf(float x) {
  union { float f; uint32_t u; } c; c.f = x;
  uint32_t r = (c.u + 0x7fffu + ((c.u >> 16) & 1u)) >> 16;  // RNE
  return (short)(r & 0xffffu);
}

__device__ __forceinline__ float dot4(float4 v) {
  return v.x * v.x + v.y * v.y + v.z * v.z + v.w * v.w;
}

__device__ __forceinline__ s8v pack8(float4 x, float4 y) {
  s8v r;
  r[0] = f2bf(x.x); r[1] = f2bf(x.y); r[2] = f2bf(x.z); r[3] = f2bf(x.w);
  r[4] = f2bf(y.x); r[5] = f2bf(y.y); r[6] = f2bf(y.z); r[7] = f2bf(y.w);
  return r;
}

// ---------------------------------------------------------------------------
// Fused kernel: phaseA (cosine-sim matrix, blocks 0..511) + convW (weight
// pack, blocks 512..2623; independent, consumed only by phaseB).
//
// phaseA v4 — DRAM-run-length fix. Rounds 0/2/3 all read each (len,b) row in
// 128B pieces at 768KB row stride -> every fetch is a DRAM page activation
// (201MB/128B ~ 1.6M activations ~ 70us = the measured floor, invariant
// across barrier/pipeline structure). Now: 3 chunks x 256 floats; each row's
// chunk is 1KB CONTIGUOUS (8 threads x 32 consecutive floats, 8 back-to-back
// dwordx4 per thread per stream). 6 barriers total. 68KB LDS -> 2 blocks/CU,
// grid 512 = fully co-resident. __launch_bounds__(512,4) caps VGPR at 128 so
// the co-resident block survives (round-3 lesson: VGPR 120+ killed it).
// ---------------------------------------------------------------------------
__global__ void __launch_bounds__(512, 4) phaseAW(const float* __restrict__ utt,
                                                  const float* __restrict__ ph,
                                                  ushort* __restrict__ Cbf,
                                                  const float* __restrict__ w_utt,
                                                  const float* __restrict__ w_ph,
                                                  ushort* __restrict__ Wbf) {
  __shared__ __align__(16) char smem[68096];      // phaseA overlay / convW tile
  const int bx = blockIdx.x;
  const int t = threadIdx.x;

  if (bx >= 512) {
    if (bx < 2560) {
      // w_utt convert: 2048 blocks x 512 thr x 1 elem -> W'[o][k]=w_utt[o,i,j]
      int idx = (bx - 512) * 512 + t;             // 0 .. 128*8192-1
      Wbf[idx] = (ushort)f2bf(w_utt[idx]);
      return;
    }
    // w_ph transpose: 64 blocks, W'[128+oc][i*64+j] = w_ph[oc,j,i]
    float* tile = (float*)smem;                   // [j][i] 64 x 129 (+1 pad)
    const int oc = bx - 2560;
    const float* src = w_ph + (size_t)oc * 8192;  // [j][i] = 64 x 128
#pragma unroll
    for (int itr = 0; itr < 4; ++itr) {
      int idx = itr * 2048 + t * 4;               // 4 consecutive i of one j
      int j = idx >> 7, i = idx & 127;
      float4 v = *(const float4*)(src + idx);     // coalesced 16B
      tile[j * 129 + i + 0] = v.x;
      tile[j * 129 + i + 1] = v.y;
      tile[j * 129 + i + 2] = v.z;
      tile[j * 129 + i + 3] = v.w;
    }
    __syncthreads();
    const size_t obase = (size_t)(128 + oc) * 8192;
#pragma unroll
    for (int itr = 0; itr < 4; ++itr) {
      int k = itr * 2048 + t * 4;                 // k = i*64 + j
      int i = k >> 6, j = k & 63;
      s4v o4 = { f2bf(tile[(j + 0) * 129 + i]),
                 f2bf(tile[(j + 1) * 129 + i]),
                 f2bf(tile[(j + 2) * 129 + i]),
                 f2bf(tile[(j + 3) * 129 + i]) };
      *(s4v*)&Wbf[obase + k] = o4;                // coalesced 8B
    }
    return;
  }

  // ---- phaseA path (blocks 0..511) ----
  // LDS overlay: uA[64][LDC] (33792B) | pB[64][LDC] (33792B) | norms (512B)
  short* uA = (short*)smem;
  short* pB = (short*)(smem + 33792);
  float* s_inu = (float*)(smem + 67584);
  float* s_inp = s_inu + 64;

  // XCD pairing: halves 0/1 of batch b are blocks bx and bx+8 -> same XCD,
  // so the shared p-panel's second read is an L2 hit.
  const int b    = (bx & 7) | ((bx >> 4) << 3);
  const int half = (bx >> 3) & 1;
  const int w = t >> 6, l = t & 63;

  const int r = t >> 3;               // 0..63: row (both u-half and p)
  const int q = t & 7;                // col-octet: floats [q*32, q*32+32)

  const size_t rstride = (size_t)Bn * Hn;
  const float* ubase = utt + (size_t)b * Hn + (size_t)(half * 64 + r) * rstride + q * 32;
  const float* pbase = ph  + (size_t)b * Hn + (size_t)r * rstride + q * 32;

  const int m  = l & 15;
  const int ko = (l >> 4) * 8;
  const int it = w & 3;               // i-tile (16 rows), 0..3
  const int jp = w >> 2;              // j-half (32 cols), 0..1
  const short* ArdU = &uA[(it * 16 + m) * LDC + ko];   // A fragment base
  const short* BrdP = &pB[(jp * 32 + m) * LDC + ko];   // B fragment base
  short* uW = &uA[r * LDC + q * 32];  // staging write base (32 bf16/thread)
  short* pW = &pB[r * LDC + q * 32];

  f4v zero4 = {0.f, 0.f, 0.f, 0.f};
  f4v acc0 = zero4, acc1 = zero4;
  float ssu = 0.f, ssp = 0.f;
  float4 u0, u1, u2, u3, u4, u5, u6, u7;
  float4 p0, p1, p2, p3, p4, p5, p6, p7;

#define LOADC(cc) do {                                                        \
    const float* up_ = ubase + (cc) * 256;                                    \
    const float* qp_ = pbase + (cc) * 256;                                    \
    u0 = *(const float4*)(up_);      u1 = *(const float4*)(up_ + 4);          \
    u2 = *(const float4*)(up_ + 8);  u3 = *(const float4*)(up_ + 12);         \
    u4 = *(const float4*)(up_ + 16); u5 = *(const float4*)(up_ + 20);         \
    u6 = *(const float4*)(up_ + 24); u7 = *(const float4*)(up_ + 28);         \
    p0 = *(const float4*)(qp_);      p1 = *(const float4*)(qp_ + 4);          \
    p2 = *(const float4*)(qp_ + 8);  p3 = *(const float4*)(qp_ + 12);         \
    p4 = *(const float4*)(qp_ + 16); p5 = *(const float4*)(qp_ + 20);         \
    p6 = *(const float4*)(qp_ + 24); p7 = *(const float4*)(qp_ + 28);         \
  } while (0)

#define STAGEC() do {                                                         \
    ssu += dot4(u0) + dot4(u1) + dot4(u2) + dot4(u3)                          \
         + dot4(u4) + dot4(u5) + dot4(u6) + dot4(u7);                         \
    ssp += dot4(p0) + dot4(p1) + dot4(p2) + dot4(p3)                          \
         + dot4(p4) + dot4(p5) + dot4(p6) + dot4(p7);                         \
    *(s8v*)(uW)      = pack8(u0, u1); *(s8v*)(uW + 8)  = pack8(u2, u3);       \
    *(s8v*)(uW + 16) = pack8(u4, u5); *(s8v*)(uW + 24) = pack8(u6, u7);       \
    *(s8v*)(pW)      = pack8(p0, p1); *(s8v*)(pW + 8)  = pack8(p2, p3);       \
    *(s8v*)(pW + 16) = pack8(p4, p5); *(s8v*)(pW + 24) = pack8(p6, p7);       \
  } while (0)

#define COMPC() do {                                                          \
    _Pragma("unroll")                                                         \
    for (int ks = 0; ks < 8; ++ks) {                                          \
      s8v af  = *(const s8v*)(ArdU + ks * 32);                                \
      s8v bf0 = *(const s8v*)(BrdP + ks * 32);                                \
      s8v bf1 = *(const s8v*)(BrdP + 16 * LDC + ks * 32);                     \
      acc0 = __builtin_amdgcn_mfma_f32_16x16x32_bf16(af, bf0, acc0, 0, 0, 0); \
      acc1 = __builtin_amdgcn_mfma_f32_16x16x32_bf16(af, bf1, acc1, 0, 0, 0); \
    }                                                                         \
  } while (0)

  // 3-chunk pipeline: chunk c+1's 16 dwordx4 issued before COMP(c) so HBM
  // latency hides under MFMA + the co-resident block; 6 barriers total.
  LOADC(0); STAGEC();
  __syncthreads();
  LOADC(1);
  COMPC();
  __syncthreads();
  STAGEC();
  __syncthreads();
  LOADC(2);
  COMPC();
  __syncthreads();
  STAGEC();
  __syncthreads();
  COMPC();

#undef LOADC
#undef STAGEC
#undef COMPC

  // row sumsq reductions: 8 threads/row are adjacent lanes (bits 0..2)
  ssu += __shfl_xor(ssu, 4); ssu += __shfl_xor(ssu, 2); ssu += __shfl_xor(ssu, 1);
  ssp += __shfl_xor(ssp, 4); ssp += __shfl_xor(ssp, 2); ssp += __shfl_xor(ssp, 1);
  if ((t & 7) == 0) {
    s_inu[r] = 1.f / fmaxf(sqrtf(ssu), 1e-8f);
    s_inp[r] = 1.f / fmaxf(sqrtf(ssp), 1e-8f);
  }
  __syncthreads();

  // epilogue: scale, store bf16 C[b][half*64+i][j]
  // D layout (verified m89/m91): col = lane&15, row = (lane>>4)*4 + reg
  const int cl = l & 15;
  const int rq = (l >> 4) * 4;
#pragma unroll
  for (int jt = 0; jt < 2; ++jt) {
    int j = jp * 32 + jt * 16 + cl;
    float sj = s_inp[j];
    f4v a = (jt == 0) ? acc0 : acc1;
#pragma unroll
    for (int rr = 0; rr < 4; ++rr) {
      int il = it * 16 + rq + rr;     // local row 0..63
      float v = a[rr] * s_inu[il] * sj;
      Cbf[((size_t)b * Un + half * 64 + il) * Pn + j] = (ushort)f2bf(v);
    }
  }
}

// ---------------------------------------------------------------------------
// Kernel 3: logits GEMM, M=256, N=192, K=8192, split-K (KC=16).
// ---------------------------------------------------------------------------
__global__ void __launch_bounds__(256) phaseB(const ushort* __restrict__ Cbf,
                                              const ushort* __restrict__ Wbf,
                                              float* __restrict__ partial) {
  const int kc = blockIdx.x;
  const int mt = blockIdx.y;
  const int nt = blockIdx.z;
  const int t = threadIdx.x;
  const int w = t >> 6, l = t & 63;

  __shared__ short Ab[64 * LDB];
  __shared__ short Bb[64 * LDB];

  const int row = t >> 2;          // 0..63
  const int k16 = (t & 3) * 16;    // 16 elems per thread per stage-row

  f4v zero4 = {0.f, 0.f, 0.f, 0.f};
  f4v acc[4] = {zero4, zero4, zero4, zero4};

  const ushort* Ag = Cbf + (size_t)(mt * 64 + row) * 8192 + kc * 512 + k16;
  const ushort* Bg = Wbf + (size_t)(nt * 64 + row) * 8192 + kc * 512 + k16;
  const int m  = l & 15;
  const int ko = (l >> 4) * 8;

  for (int c = 0; c < 8; ++c) {
    s8v av0 = *(const s8v*)(Ag + c * 64);
    s8v av1 = *(const s8v*)(Ag + c * 64 + 8);
    s8v bv0 = *(const s8v*)(Bg + c * 64);
    s8v bv1 = *(const s8v*)(Bg + c * 64 + 8);
    __syncthreads();
    *(s8v*)&Ab[row * LDB + k16]     = av0;
    *(s8v*)&Ab[row * LDB + k16 + 8] = av1;
    *(s8v*)&Bb[row * LDB + k16]     = bv0;
    *(s8v*)&Bb[row * LDB + k16 + 8] = bv1;
    __syncthreads();
#pragma unroll
    for (int ks = 0; ks < 2; ++ks) {
      s8v af = *(const s8v*)&Ab[(16 * w + m) * LDB + ks * 32 + ko];
#pragma unroll
      for (int jt = 0; jt < 4; ++jt) {
        s8v bf = *(const s8v*)&Bb[(16 * jt + m) * LDB + ks * 32 + ko];
        acc[jt] = __builtin_amdgcn_mfma_f32_16x16x32_bf16(af, bf, acc[jt], 0, 0, 0);
      }
    }
  }

  const int rq = (l >> 4) * 4;
#pragma unroll
  for (int jt = 0; jt < 4; ++jt) {
    int og = nt * 64 + 16 * jt + (l & 15);
#pragma unroll
    for (int r = 0; r < 4; ++r) {
      int bg = mt * 64 + 16 * w + rq + r;
      partial[((size_t)kc * Bn + bg) * Ototal + og] = acc[jt][r];
    }
  }
}

// ---------------------------------------------------------------------------
// Kernel 4: reduce split-K partials + bias + dual-group softmax.
// ---------------------------------------------------------------------------
__global__ void __launch_bounds__(192) phaseC(const float* __restrict__ partial,
                                              const float* __restrict__ b_utt,
                                              const float* __restrict__ b_ph,
                                              float* __restrict__ out) {
  const int b = blockIdx.x;
  const int t = threadIdx.x;      // 0..191
  const int w = t >> 6, l = t & 63;

  float v = 0.f;
#pragma unroll
  for (int kc = 0; kc < KC; ++kc)
    v += partial[((size_t)kc * Bn + b) * Ototal + t];
  v += (t < Un) ? b_utt[t] : b_ph[t - Un];

  __shared__ float red[3];
  float mx = v;
  for (int o = 32; o >= 1; o >>= 1) mx = fmaxf(mx, __shfl_xor(mx, o));
  if (l == 0) red[w] = mx;
  __syncthreads();
  float gmax = (t < Un) ? fmaxf(red[0], red[1]) : red[2];
  float e = expf(v - gmax);
  float s = e;
  for (int o = 32; o >= 1; o >>= 1) s += __shfl_xor(s, o);
  __syncthreads();
  if (l == 0) red[w] = s;
  __syncthreads();
  float gs = (t < Un) ? (red[0] + red[1]) : red[2];
  float r = e / gs;
  if (t < Un) out[(size_t)b * Un + t] = r;
  else        out[(size_t)Bn * Un + (size_t)b * Pn + (t - Un)] = r;
}

// ---------------------------------------------------------------------------
extern "C" void kernel_launch(void* const* d_in, const int* in_sizes, int n_in,
                              void* d_out, int out_size, void* d_ws, size_t ws_size,
                              hipStream_t stream) {
  const float* utt   = (const float*)d_in[0];  // [128,256,768]
  const float* ph    = (const float*)d_in[1];  // [64,256,768]
  const float* w_utt = (const float*)d_in[2];  // [128,128,64]
  const float* b_utt = (const float*)d_in[3];  // [128]
  const float* w_ph  = (const float*)d_in[4];  // [64,64,128]
  const float* b_ph  = (const float*)d_in[5];  // [64]

  char* ws = (char*)d_ws;
  ushort* Cbf     = (ushort*)(ws);                 // 256*128*64*2  = 4 MiB
  ushort* Wbf     = (ushort*)(ws + 4194304);       // 192*8192*2   = 3 MiB
  float*  partial = (float*)(ws + 7340032);        // 16*256*192*4 = 3 MiB

  phaseAW<<<dim3(2624), dim3(512), 0, stream>>>(utt, ph, Cbf, w_utt, w_ph, Wbf);
  phaseB <<<dim3(KC, 4, 3), dim3(256), 0, stream>>>(Cbf, Wbf, partial);
  phaseC <<<dim3(Bn), dim3(192), 0, stream>>>(partial, b_utt, b_ph, (float*)d_out);
}

// Round 5
// 254.102 us; speedup vs baseline: 1.1269x; 1.1269x over previous
//
#include <hip/hip_runtime.h>
#include <stdint.h>

// Shapes (fixed by the problem)
#define Bn 256
#define Un 128
#define Pn 64
#define Hn 768
#define Ototal 192   // 128 row-logit outputs + 64 col-logit outputs
#define KC 16        // split-K chunks in phase B (K=8192 -> 512 each)

#define LDA 72       // phaseA LDS row stride (ushorts): 144B = 9*16 (b128-aligned)
#define LDB 72       // phaseB LDS row stride (ushorts)

typedef short s4v __attribute__((ext_vector_type(4)));
typedef short s8v __attribute__((ext_vector_type(8)));
typedef float f4v __attribute__((ext_vector_type(4)));

__device__ __forceinline__ short f2bf(float x) {
  union { float f; uint32_t u; } c; c.f = x;
  uint32_t r = (c.u + 0x7fffu + ((c.u >> 16) & 1u)) >> 16;  // RNE
  return (short)(r & 0xffffu);
}

__device__ __forceinline__ float dot4(float4 v) {
  return v.x * v.x + v.y * v.y + v.z * v.z + v.w * v.w;
}

__device__ __forceinline__ s8v pack8(float4 x, float4 y) {
  s8v r;
  r[0] = f2bf(x.x); r[1] = f2bf(x.y); r[2] = f2bf(x.z); r[3] = f2bf(x.w);
  r[4] = f2bf(y.x); r[5] = f2bf(y.y); r[6] = f2bf(y.z); r[7] = f2bf(y.w);
  return r;
}

// ---------------------------------------------------------------------------
// Fused kernel: phaseA (blocks 0..255) + convW (blocks 256..2367).
//
// phaseA v5 — SINGLE-PASS per batch. Rounds 0-3 read the p-panel twice
// (two half-blocks per batch): CU-side demand 201MB at the observed ~3TB/s
// demand ceiling = the 68us floor. Round 4 showed the failure mode of wide
// staging: 64 VGPR of live float4 under a (512,4) cap -> 205MB scratch
// writes. v5: ONE block per batch computes the full 128x64 tile, so u and p
// are each read exactly once (144MB total demand, -28%). K-chunk = 64 floats
// (256B contiguous per row, 2x r2's run length); per-thread staging = 6
// float4 = 24 VGPR (r4's killer removed); 12 chunks x 1 barrier (r2's
// verified single-barrier double-buffer). launch_bounds(512,2): no spill.
// ---------------------------------------------------------------------------
__global__ void __launch_bounds__(512, 2) phaseAW(const float* __restrict__ utt,
                                                  const float* __restrict__ ph,
                                                  ushort* __restrict__ Cbf,
                                                  const float* __restrict__ w_utt,
                                                  const float* __restrict__ w_ph,
                                                  ushort* __restrict__ Wbf) {
  __shared__ __align__(16) char smem[56064];
  const int bx = blockIdx.x;
  const int t = threadIdx.x;

  if (bx >= 256) {
    if (bx < 2304) {
      // w_utt convert: 2048 blocks x 512 thr x 1 elem -> W'[o][k]=w_utt[o,i,j]
      int idx = (bx - 256) * 512 + t;             // 0 .. 128*8192-1
      Wbf[idx] = (ushort)f2bf(w_utt[idx]);
      return;
    }
    // w_ph transpose: 64 blocks, W'[128+oc][i*64+j] = w_ph[oc,j,i]
    float* tile = (float*)smem;                   // [j][i] 64 x 129 (+1 pad)
    const int oc = bx - 2304;
    const float* src = w_ph + (size_t)oc * 8192;  // [j][i] = 64 x 128
#pragma unroll
    for (int itr = 0; itr < 4; ++itr) {
      int idx = itr * 2048 + t * 4;               // 4 consecutive i of one j
      int j = idx >> 7, i = idx & 127;
      float4 v = *(const float4*)(src + idx);     // coalesced 16B
      tile[j * 129 + i + 0] = v.x;
      tile[j * 129 + i + 1] = v.y;
      tile[j * 129 + i + 2] = v.z;
      tile[j * 129 + i + 3] = v.w;
    }
    __syncthreads();
    const size_t obase = (size_t)(128 + oc) * 8192;
#pragma unroll
    for (int itr = 0; itr < 4; ++itr) {
      int k = itr * 2048 + t * 4;                 // k = i*64 + j
      int i = k >> 6, j = k & 63;
      s4v o4 = { f2bf(tile[(j + 0) * 129 + i]),
                 f2bf(tile[(j + 1) * 129 + i]),
                 f2bf(tile[(j + 2) * 129 + i]),
                 f2bf(tile[(j + 3) * 129 + i]) };
      *(s4v*)&Wbf[obase + k] = o4;                // coalesced 8B
    }
    return;
  }

  // ---- phaseA path (blocks 0..255): batch b = bx, full 128x64 tile ----
  // LDS: uA[2][128*LDA] (36864B) | pB[2][64*LDA] (18432B) | inu[128] | inp[64]
  short (*uA)[128 * LDA] = (short (*)[128 * LDA])(smem);
  short (*pB)[64 * LDA]  = (short (*)[64 * LDA])(smem + 36864);
  float* s_inu = (float*)(smem + 55296);
  float* s_inp = (float*)(smem + 55808);

  const int b = bx;
  const int w = t >> 6, l = t & 63;   // 8 waves; wave w owns u-rows w*16..+16

  // staging ownership (fixed row per thread for both streams)
  const int ur = t >> 2;              // u-row 0..127 (4 thr/row)
  const int uq = t & 3;               //   16-float segment within chunk
  const int pr = t >> 3;              // p-row 0..63  (8 thr/row)
  const int pq = t & 7;               //   8-float segment within chunk

  const size_t RS = (size_t)Bn * Hn;
  const float* ug = utt + (size_t)ur * RS + (size_t)b * Hn + uq * 16;
  const float* pg = ph  + (size_t)pr * RS + (size_t)b * Hn + pq * 8;
  short* uw0 = &uA[0][ur * LDA + uq * 16];
  short* uw1 = &uA[1][ur * LDA + uq * 16];
  short* pw0 = &pB[0][pr * LDA + pq * 8];
  short* pw1 = &pB[1][pr * LDA + pq * 8];

  // MFMA fragment bases: wave w = u-tile (rows w*16..), all 4 p-tiles
  const int m  = l & 15;
  const int ko = (l >> 4) * 8;
  const int aoff = (w * 16 + m) * LDA + ko;

  f4v zero4 = {0.f, 0.f, 0.f, 0.f};
  f4v acc[4] = {zero4, zero4, zero4, zero4};
  float ssu = 0.f, ssp = 0.f;
  float4 u0, u1, u2, u3, p0, p1;

#define LOADR(cc) do {                                                        \
    const float* up_ = ug + (cc) * 64;                                        \
    const float* qp_ = pg + (cc) * 64;                                        \
    u0 = *(const float4*)(up_);      u1 = *(const float4*)(up_ + 4);          \
    u2 = *(const float4*)(up_ + 8);  u3 = *(const float4*)(up_ + 12);         \
    p0 = *(const float4*)(qp_);      p1 = *(const float4*)(qp_ + 4);          \
  } while (0)

#define STAGER(uw, pw) do {                                                   \
    ssu += dot4(u0) + dot4(u1) + dot4(u2) + dot4(u3);                         \
    ssp += dot4(p0) + dot4(p1);                                               \
    *(s8v*)(uw)     = pack8(u0, u1);                                          \
    *(s8v*)((uw)+8) = pack8(u2, u3);                                          \
    *(s8v*)(pw)     = pack8(p0, p1);                                          \
  } while (0)

#define COMPR(buf) do {                                                       \
    _Pragma("unroll")                                                         \
    for (int ks = 0; ks < 2; ++ks) {                                          \
      s8v af = *(const s8v*)&uA[buf][aoff + ks * 32];                         \
      _Pragma("unroll")                                                       \
      for (int jt = 0; jt < 4; ++jt) {                                        \
        s8v bf = *(const s8v*)&pB[buf][(jt * 16 + m) * LDA + ks * 32 + ko];   \
        acc[jt] = __builtin_amdgcn_mfma_f32_16x16x32_bf16(af, bf, acc[jt],    \
                                                          0, 0, 0);           \
      }                                                                       \
    }                                                                         \
  } while (0)

  LOADR(0);
  STAGER(uw0, pw0);
  __syncthreads();

#pragma unroll
  for (int c = 0; c < 12; ++c) {
    if (c < 11) LOADR(c + 1);         // in flight across COMP (counted vmcnt)
    COMPR(c & 1);
    if (c < 11) {                     // convert+stage into the other buffer
      if (c & 1) STAGER(uw0, pw0); else STAGER(uw1, pw1);
    }
    __syncthreads();                  // one barrier per chunk (r2 scheme)
  }

#undef LOADR
#undef STAGER
#undef COMPR

  // norms: u-row shared by 4 adjacent lanes, p-row by 8 adjacent lanes
  ssu += __shfl_xor(ssu, 2); ssu += __shfl_xor(ssu, 1);
  ssp += __shfl_xor(ssp, 4); ssp += __shfl_xor(ssp, 2); ssp += __shfl_xor(ssp, 1);
  if ((t & 3) == 0) s_inu[ur] = 1.f / fmaxf(sqrtf(ssu), 1e-8f);
  if ((t & 7) == 0) s_inp[pr] = 1.f / fmaxf(sqrtf(ssp), 1e-8f);
  __syncthreads();

  // epilogue: scale, store bf16 C[b][row][j]
  // D layout (phaseB-verified): col = lane&15, row = (lane>>4)*4 + reg
  const int cl = l & 15;
  const int rq = (l >> 4) * 4;
#pragma unroll
  for (int jt = 0; jt < 4; ++jt) {
    int j = jt * 16 + cl;
    float sj = s_inp[j];
#pragma unroll
    for (int rr = 0; rr < 4; ++rr) {
      int row = w * 16 + rq + rr;     // 0..127
      float v = acc[jt][rr] * s_inu[row] * sj;
      Cbf[((size_t)b * Un + row) * Pn + j] = (ushort)f2bf(v);
    }
  }
}

// ---------------------------------------------------------------------------
// Kernel 3: logits GEMM, M=256, N=192, K=8192, split-K (KC=16).
// ---------------------------------------------------------------------------
__global__ void __launch_bounds__(256) phaseB(const ushort* __restrict__ Cbf,
                                              const ushort* __restrict__ Wbf,
                                              float* __restrict__ partial) {
  const int kc = blockIdx.x;
  const int mt = blockIdx.y;
  const int nt = blockIdx.z;
  const int t = threadIdx.x;
  const int w = t >> 6, l = t & 63;

  __shared__ short Ab[64 * LDB];
  __shared__ short Bb[64 * LDB];

  const int row = t >> 2;          // 0..63
  const int k16 = (t & 3) * 16;    // 16 elems per thread per stage-row

  f4v zero4 = {0.f, 0.f, 0.f, 0.f};
  f4v acc[4] = {zero4, zero4, zero4, zero4};

  const ushort* Ag = Cbf + (size_t)(mt * 64 + row) * 8192 + kc * 512 + k16;
  const ushort* Bg = Wbf + (size_t)(nt * 64 + row) * 8192 + kc * 512 + k16;
  const int m  = l & 15;
  const int ko = (l >> 4) * 8;

  for (int c = 0; c < 8; ++c) {
    s8v av0 = *(const s8v*)(Ag + c * 64);
    s8v av1 = *(const s8v*)(Ag + c * 64 + 8);
    s8v bv0 = *(const s8v*)(Bg + c * 64);
    s8v bv1 = *(const s8v*)(Bg + c * 64 + 8);
    __syncthreads();
    *(s8v*)&Ab[row * LDB + k16]     = av0;
    *(s8v*)&Ab[row * LDB + k16 + 8] = av1;
    *(s8v*)&Bb[row * LDB + k16]     = bv0;
    *(s8v*)&Bb[row * LDB + k16 + 8] = bv1;
    __syncthreads();
#pragma unroll
    for (int ks = 0; ks < 2; ++ks) {
      s8v af = *(const s8v*)&Ab[(16 * w + m) * LDB + ks * 32 + ko];
#pragma unroll
      for (int jt = 0; jt < 4; ++jt) {
        s8v bf = *(const s8v*)&Bb[(16 * jt + m) * LDB + ks * 32 + ko];
        acc[jt] = __builtin_amdgcn_mfma_f32_16x16x32_bf16(af, bf, acc[jt], 0, 0, 0);
      }
    }
  }

  const int rq = (l >> 4) * 4;
#pragma unroll
  for (int jt = 0; jt < 4; ++jt) {
    int og = nt * 64 + 16 * jt + (l & 15);
#pragma unroll
    for (int r = 0; r < 4; ++r) {
      int bg = mt * 64 + 16 * w + rq + r;
      partial[((size_t)kc * Bn + bg) * Ototal + og] = acc[jt][r];
    }
  }
}

// ---------------------------------------------------------------------------
// Kernel 4: reduce split-K partials + bias + dual-group softmax.
// ---------------------------------------------------------------------------
__global__ void __launch_bounds__(192) phaseC(const float* __restrict__ partial,
                                              const float* __restrict__ b_utt,
                                              const float* __restrict__ b_ph,
                                              float* __restrict__ out) {
  const int b = blockIdx.x;
  const int t = threadIdx.x;      // 0..191
  const int w = t >> 6, l = t & 63;

  float v = 0.f;
#pragma unroll
  for (int kc = 0; kc < KC; ++kc)
    v += partial[((size_t)kc * Bn + b) * Ototal + t];
  v += (t < Un) ? b_utt[t] : b_ph[t - Un];

  __shared__ float red[3];
  float mx = v;
  for (int o = 32; o >= 1; o >>= 1) mx = fmaxf(mx, __shfl_xor(mx, o));
  if (l == 0) red[w] = mx;
  __syncthreads();
  float gmax = (t < Un) ? fmaxf(red[0], red[1]) : red[2];
  float e = expf(v - gmax);
  float s = e;
  for (int o = 32; o >= 1; o >>= 1) s += __shfl_xor(s, o);
  __syncthreads();
  if (l == 0) red[w] = s;
  __syncthreads();
  float gs = (t < Un) ? (red[0] + red[1]) : red[2];
  float r = e / gs;
  if (t < Un) out[(size_t)b * Un + t] = r;
  else        out[(size_t)Bn * Un + (size_t)b * Pn + (t - Un)] = r;
}

// ---------------------------------------------------------------------------
extern "C" void kernel_launch(void* const* d_in, const int* in_sizes, int n_in,
                              void* d_out, int out_size, void* d_ws, size_t ws_size,
                              hipStream_t stream) {
  const float* utt   = (const float*)d_in[0];  // [128,256,768]
  const float* ph    = (const float*)d_in[1];  // [64,256,768]
  const float* w_utt = (const float*)d_in[2];  // [128,128,64]
  const float* b_utt = (const float*)d_in[3];  // [128]
  const float* w_ph  = (const float*)d_in[4];  // [64,64,128]
  const float* b_ph  = (const float*)d_in[5];  // [64]

  char* ws = (char*)d_ws;
  ushort* Cbf     = (ushort*)(ws);                 // 256*128*64*2  = 4 MiB
  ushort* Wbf     = (ushort*)(ws + 4194304);       // 192*8192*2   = 3 MiB
  float*  partial = (float*)(ws + 7340032);        // 16*256*192*4 = 3 MiB

  phaseAW<<<dim3(2368), dim3(512), 0, stream>>>(utt, ph, Cbf, w_utt, w_ph, Wbf);
  phaseB <<<dim3(KC, 4, 3), dim3(256), 0, stream>>>(Cbf, Wbf, partial);
  phaseC <<<dim3(Bn), dim3(192), 0, stream>>>(partial, b_utt, b_ph, (float*)d_out);
}